// Round 2
// baseline (161.112 us; speedup 1.0000x reference)
//
#include <hip/hip_runtime.h>
#include <math.h>

constexpr int L = 32768;
constexpr int H = 256;
constexpr int P = 256;
constexpr int T = 64;        // scan chunk length
constexpr int NC = L / T;    // 512 chunks
constexpr int N1 = 2 * P;    // 512: X concat width, INTERLEAVED col = 2p+{0:re,1:im}
constexpr int LDA = 40;      // padded LDS A row stride (shorts): conflict-free frag reads
constexpr int LDEP = 130;    // epilogue LDS row stride (floats)

typedef __attribute__((ext_vector_type(8))) short short8;
typedef __attribute__((ext_vector_type(4))) float f32x4;

// ---------------- bf16 helpers (RNE) ----------------
__device__ __forceinline__ unsigned f2bf(float f) {
  unsigned u = __float_as_uint(f);
  return (u + 0x7FFFu + ((u >> 16) & 1u)) >> 16;
}
__device__ __forceinline__ float bf_lo(unsigned u) { return __uint_as_float(u << 16); }
__device__ __forceinline__ float bf_hi(unsigned u) { return __uint_as_float(u & 0xFFFF0000u); }

__device__ __forceinline__ void gload_lds16(const unsigned short* g, unsigned short* l) {
  __builtin_amdgcn_global_load_lds(
      (const __attribute__((address_space(1))) unsigned int*)(g),
      (__attribute__((address_space(3))) unsigned int*)(l), 16, 0, 0);
}

// Counted-vmcnt barrier: oldest B-tile gloads must have landed, deeper
// prefetches stay in flight. lgkmcnt(0) publishes this wave's ds_writes and
// completes its ds_reads before the barrier (DS retires in order).
#define KBAR(N) do { \
    asm volatile("s_waitcnt vmcnt(" #N ") lgkmcnt(0)" ::: "memory"); \
    __builtin_amdgcn_s_barrier(); \
    __builtin_amdgcn_sched_barrier(0); \
  } while (0)

// Pin VMEM issue order (ALU/VALU/SALU/MFMA/DS may cross, VMEM may not).
#define VMEM_FENCE() __builtin_amdgcn_sched_barrier(0x38F)

__device__ __forceinline__ void lambda_bar_of(const float* __restrict__ lam,
                                              const float* __restrict__ lstep,
                                              int p, float& lbr, float& lbi) {
  float lr = lam[2 * p], li = lam[2 * p + 1];
  float st = expf(lstep[p]);
  float ea = expf(lr * st);
  lbr = ea * cosf(li * st);
  lbi = ea * sinf(li * st);
}

// ---------------------------------------------------------------------------
// k_prep: Bcat (512 x 256 bf16, rows interleaved: row 2p=Re(B_bar[p]), 2p+1=Im)
//         Ccat (256 x 512 bf16, cols interleaved: col 2p=Re(C[h,p]), 2p+1=-Im)
//         pow  (T x P fp32 planar): lambda_bar^(t+1)
// ---------------------------------------------------------------------------
__global__ __launch_bounds__(256) void k_prep(const float* __restrict__ lam,
                                              const float* __restrict__ lstep,
                                              const float* __restrict__ Bri,
                                              const float* __restrict__ Cri,
                                              unsigned short* __restrict__ Bcat,
                                              unsigned short* __restrict__ Ccat,
                                              float* __restrict__ powr,
                                              float* __restrict__ powi) {
  int idx = blockIdx.x * 256 + threadIdx.x;  // < 278528
  if (idx < N1 * H) {
    int n = idx >> 8, k = idx & 255;
    int p = n >> 1, comp = n & 1;
    float lr = lam[2 * p], li = lam[2 * p + 1];
    float st = expf(lstep[p]);
    float ea = expf(lr * st);
    float lbr = ea * cosf(li * st), lbi = ea * sinf(li * st);
    float inv = 1.0f / (lr * lr + li * li);
    float nr = lbr - 1.0f;
    float fr = (nr * lr + lbi * li) * inv;
    float fi = (lbi * lr - nr * li) * inv;
    float br = Bri[2 * (p * H + k)], bi = Bri[2 * (p * H + k) + 1];
    float v = (comp == 0) ? (fr * br - fi * bi) : (fr * bi + fi * br);
    Bcat[idx] = (unsigned short)f2bf(v);
  } else if (idx < 2 * N1 * H) {
    int j = idx - N1 * H;
    int h = j >> 9, k2 = j & 511;
    int p = k2 >> 1;
    float v = ((k2 & 1) == 0) ? Cri[2 * (h * P + p)] : -Cri[2 * (h * P + p) + 1];
    Ccat[j] = (unsigned short)f2bf(v);
  } else {
    int r = idx - 2 * N1 * H;  // < T*P
    int t = r >> 8, p = r & 255;
    float lr = lam[2 * p], li = lam[2 * p + 1];
    float st = expf(lstep[p]);
    float e = (float)(t + 1);
    float er = expf(e * lr * st);
    powr[r] = er * cosf(e * li * st);
    powi[r] = er * sinf(e * li * st);
  }
}

// ---------------------------------------------------------------------------
// GEMM1 fused: 128x128 tile (2 chunks). B: 4-deep LDS ring via global_load_lds
// (fragment-major, conflict-free); A: depth-3 reg pipeline (2 bufs). Counted
// vmcnt barriers, 3 iterations of latency cover on every stream.
// Epilogue: per-chunk LDS dump + in-block scan -> Xl (bf16 interleaved) + S.
// grid (L/128, N1/128) = (256, 4).  S stored TRANSPOSED: [p][NC].
// ---------------------------------------------------------------------------
__global__ __launch_bounds__(256, 3) void k_gemm1s(const float* __restrict__ sig,
                                                   const unsigned short* __restrict__ Bcat,
                                                   const float* __restrict__ lam,
                                                   const float* __restrict__ lstep,
                                                   unsigned short* __restrict__ Xl,
                                                   float* __restrict__ Sr,
                                                   float* __restrict__ Si) {
  constexpr int K = 256, NIT = K / 32;
  __shared__ __align__(16) char smem[53248];
  unsigned short* sA[2] = {(unsigned short*)smem, (unsigned short*)smem + 5120};
  unsigned short* sB[4] = {(unsigned short*)(smem + 20480), (unsigned short*)(smem + 28672),
                           (unsigned short*)(smem + 36864), (unsigned short*)(smem + 45056)};
  float* sEpi = (float*)smem;
  const int tid = threadIdx.x;
  const int lane = tid & 63;
  const int wave = tid >> 6;
  const int wr = (wave >> 1) * 64, wc = (wave & 1) * 64;
  const int m0 = blockIdx.x * 128, n0 = blockIdx.y * 128;
  const int ar = tid >> 1, aq = (tid & 1) * 16;       // A staging: row 0..127, 16-elem half
  const int brow = ((tid >> 6) << 4) | (tid & 15);    // B staging: fragment-major source row
  const int bko = ((tid >> 4) & 3) * 8;               // B staging: k-subgroup (8 shorts)
  const int frow = lane & 15, fk = (lane >> 4) * 8;
  const int hb = (wave & 1) * 2048;                   // this wave's B half base (shorts)
  f32x4 acc[4][4];
#pragma unroll
  for (int i = 0; i < 4; i++)
#pragma unroll
    for (int j = 0; j < 4; j++) acc[i][j] = (f32x4){0.f, 0.f, 0.f, 0.f};

  float4 aR0[4], aR1[4];
  const float* abase = sig + (size_t)(m0 + ar) * K + aq;
#define LOAD_A(R, k0) { const float* s_ = abase + (k0); \
    R[0] = *(const float4*)(s_); R[1] = *(const float4*)(s_ + 4); \
    R[2] = *(const float4*)(s_ + 8); R[3] = *(const float4*)(s_ + 12); }
#define WRITE_A(R, dst) { uint4 w0, w1; \
    w0.x = f2bf(R[0].x) | (f2bf(R[0].y) << 16); w0.y = f2bf(R[0].z) | (f2bf(R[0].w) << 16); \
    w0.z = f2bf(R[1].x) | (f2bf(R[1].y) << 16); w0.w = f2bf(R[1].z) | (f2bf(R[1].w) << 16); \
    w1.x = f2bf(R[2].x) | (f2bf(R[2].y) << 16); w1.y = f2bf(R[2].z) | (f2bf(R[2].w) << 16); \
    w1.z = f2bf(R[3].x) | (f2bf(R[3].y) << 16); w1.w = f2bf(R[3].z) | (f2bf(R[3].w) << 16); \
    *(uint4*)((dst) + ar * LDA + aq) = w0; *(uint4*)((dst) + ar * LDA + aq + 8) = w1; }
#define ISSUE_B(k0, buf) { \
    gload_lds16(Bcat + (size_t)(n0 + brow) * K + (k0) + bko, sB[buf] + tid * 8); \
    gload_lds16(Bcat + (size_t)(n0 + 64 + brow) * K + (k0) + bko, sB[buf] + 2048 + tid * 8); }

  // prologue. VMEM issue order: A0(4) A1(4) B0(2) B1(2) B2(2) A2(4).
  LOAD_A(aR0, 0);
  LOAD_A(aR1, 32);
  VMEM_FENCE();
  ISSUE_B(0, 0);
  ISSUE_B(32, 1);
  ISSUE_B(64, 2);
  VMEM_FENCE();
  WRITE_A(aR0, sA[0]);   // consumes A0 (implicit wait leaves 10)
  LOAD_A(aR0, 64);       // A2
  VMEM_FENCE();
  KBAR(8);               // wait B0: newer = B1(2)+B2(2)+A2(4)
#pragma unroll
  for (int it = 0; it < NIT; it++) {
    // consume tile it+1's regs -> LDS (implicit wait leaves ~8)
    if (it + 1 < NIT) {
      if (((it + 1) & 1) == 0) { WRITE_A(aR0, sA[0]); } else { WRITE_A(aR1, sA[1]); }
    }
    VMEM_FENCE();
    // reg-stream loads FIRST (so future consume-waits leave B outstanding)
    if (it + 3 < NIT) {
      if (((it + 3) & 1) == 0) { LOAD_A(aR0, (it + 3) * 32); } else { LOAD_A(aR1, (it + 3) * 32); }
    }
    VMEM_FENCE();
    if (it + 3 < NIT) ISSUE_B((it + 3) * 32, (it + 3) & 3);
    VMEM_FENCE();
    short8 af[4], bfr[4];
#pragma unroll
    for (int i = 0; i < 4; i++) af[i] = *(const short8*)(sA[it & 1] + (wr + i * 16 + frow) * LDA + fk);
#pragma unroll
    for (int j = 0; j < 4; j++) bfr[j] = *(const short8*)(sB[it & 3] + hb + (j * 64 + lane) * 8);
#pragma unroll
    for (int i = 0; i < 4; i++)
#pragma unroll
      for (int j = 0; j < 4; j++)
        acc[i][j] = __builtin_amdgcn_mfma_f32_16x16x32_bf16(af[i], bfr[j], acc[i][j], 0, 0, 0);
    // wait B(it+1): steady newer = A(it+2)4+B(it+2)2+A(it+3)4+B(it+3)2 = 12
    if (it + 1 < NIT) {
      if (it < NIT - 3) { KBAR(12); }
      else if (it == NIT - 3) { KBAR(6); }
      else { KBAR(0); }
    }
  }
  __syncthreads();

  // ---- epilogue: per chunk-half: dump rows to LDS, scan, store ----
  const int crow = (lane >> 4) * 4, ccol = wc + (lane & 15);
#pragma unroll
  for (int half = 0; half < 2; half++) {
    if ((wave >> 1) == half) {
#pragma unroll
      for (int i = 0; i < 4; i++)
#pragma unroll
        for (int j = 0; j < 4; j++)
#pragma unroll
          for (int g = 0; g < 4; g++)
            sEpi[(crow + i * 16 + g) * LDEP + ccol + j * 16] = acc[i][j][g];
    }
    __syncthreads();
    if (tid < 64) {
      const int pl = tid;
      const int gp = (n0 >> 1) + pl;
      const int c = blockIdx.x * 2 + half;
      float lbr, lbi;
      lambda_bar_of(lam, lstep, gp, lbr, lbi);
      float xr = 0.f, xi = 0.f;
      const float* e = sEpi + 2 * pl;
      const size_t gbase = (size_t)(m0 + half * 64) * N1 + n0 + 2 * pl;
      for (int tb = 0; tb < T; tb += 8) {
        float2 v[8];
#pragma unroll
        for (int u = 0; u < 8; u++) v[u] = *(const float2*)(e + (tb + u) * LDEP);
        unsigned ov[8];
#pragma unroll
        for (int u = 0; u < 8; u++) {
          float nr = fmaf(lbr, xr, fmaf(-lbi, xi, v[u].x));
          float ni = fmaf(lbr, xi, fmaf(lbi, xr, v[u].y));
          xr = nr; xi = ni;
          ov[u] = f2bf(xr) | (f2bf(xi) << 16);
        }
#pragma unroll
        for (int u = 0; u < 8; u++)
          *(unsigned*)(Xl + gbase + (size_t)(tb + u) * N1) = ov[u];
      }
      Sr[(size_t)gp * NC + c] = xr;   // TRANSPOSED [p][NC]
      Si[(size_t)gp * NC + c] = xi;
    }
    __syncthreads();
  }
#undef LOAD_A
#undef WRITE_A
#undef ISSUE_B
}

// ---------------------------------------------------------------------------
// Parallel carry scan: 256 blocks (one per p) x 64 threads (1 wave).
// S is [p][NC] -> vectorized contiguous loads.
// ---------------------------------------------------------------------------
__global__ __launch_bounds__(64) void k_carry2(const float* __restrict__ lam,
                                               const float* __restrict__ lstep,
                                               const float* __restrict__ Sr,
                                               const float* __restrict__ Si,
                                               float* __restrict__ car, float* __restrict__ cai) {
  const int p = blockIdx.x;
  const int t = threadIdx.x;  // 0..63
  float lr = lam[2 * p], li = lam[2 * p + 1];
  float st = expf(lstep[p]);
  float eT = expf((float)T * lr * st);
  float lTr = eT * cosf((float)T * li * st);
  float lTi = eT * sinf((float)T * li * st);
  float vr[8], vi[8];
  {
    const float* srp = Sr + (size_t)p * NC + t * 8;
    const float* sip = Si + (size_t)p * NC + t * 8;
    float4 a0 = *(const float4*)(srp), a1 = *(const float4*)(srp + 4);
    float4 b0 = *(const float4*)(sip), b1 = *(const float4*)(sip + 4);
    vr[0] = a0.x; vr[1] = a0.y; vr[2] = a0.z; vr[3] = a0.w;
    vr[4] = a1.x; vr[5] = a1.y; vr[6] = a1.z; vr[7] = a1.w;
    vi[0] = b0.x; vi[1] = b0.y; vi[2] = b0.z; vi[3] = b0.w;
    vi[4] = b1.x; vi[5] = b1.y; vi[6] = b1.z; vi[7] = b1.w;
  }
  float Br = 0.f, Bi = 0.f;
#pragma unroll
  for (int u = 0; u < 8; u++) {
    float nr = fmaf(lTr, Br, fmaf(-lTi, Bi, vr[u]));
    float ni = fmaf(lTr, Bi, fmaf(lTi, Br, vi[u]));
    Br = nr; Bi = ni;
  }
  float e8 = expf(8.0f * (float)T * lr * st);
  float Ar = e8 * cosf(8.0f * (float)T * li * st);
  float Ai = e8 * sinf(8.0f * (float)T * li * st);
#pragma unroll
  for (int d = 1; d < 64; d <<= 1) {
    float Aor = __shfl_up(Ar, d), Aoi = __shfl_up(Ai, d);
    float Bor = __shfl_up(Br, d), Boi = __shfl_up(Bi, d);
    if (t >= d) {
      float nBr = Ar * Bor - Ai * Boi + Br;
      float nBi = Ar * Boi + Ai * Bor + Bi;
      float nAr = Aor * Ar - Aoi * Ai;
      float nAi = Aor * Ai + Aoi * Ar;
      Br = nBr; Bi = nBi; Ar = nAr; Ai = nAi;
    }
  }
  float cr = __shfl_up(Br, 1), ci = __shfl_up(Bi, 1);
  if (t == 0) { cr = 0.f; ci = 0.f; }
#pragma unroll
  for (int u = 0; u < 8; u++) {
    car[(t * 8 + u) * P + p] = cr;
    cai[(t * 8 + u) * P + p] = ci;
    float nr = fmaf(lTr, cr, fmaf(-lTi, ci, vr[u]));
    float ni = fmaf(lTr, ci, fmaf(lTi, cr, vi[u]));
    cr = nr; ci = ni;
  }
}

// ---------------------------------------------------------------------------
// GEMM2 fused: 128x128 tile (2 chunks). B(Ccat): 4-deep LDS ring; X and
// pow/carry: depth-3 reg pipelines (2 bufs each). Counted vmcnt barriers.
// grid (L/128, H/128) = (256, 2).
// ---------------------------------------------------------------------------
__global__ __launch_bounds__(256, 3) void k_gemm2f(const unsigned short* __restrict__ Xl,
                                                   const unsigned short* __restrict__ Ccat,
                                                   const float* __restrict__ powr,
                                                   const float* __restrict__ powi,
                                                   const float* __restrict__ car,
                                                   const float* __restrict__ cai,
                                                   const float* __restrict__ sig,
                                                   const float* __restrict__ Dv,
                                                   float* __restrict__ out) {
  constexpr int K = 512, NIT = K / 32;
  __shared__ __align__(16) char smem[53248];
  unsigned short* sA[2] = {(unsigned short*)smem, (unsigned short*)smem + 5120};
  unsigned short* sB[4] = {(unsigned short*)(smem + 20480), (unsigned short*)(smem + 28672),
                           (unsigned short*)(smem + 36864), (unsigned short*)(smem + 45056)};
  const int tid = threadIdx.x;
  const int lane = tid & 63;
  const int wave = tid >> 6;
  const int wr = (wave >> 1) * 64, wc = (wave & 1) * 64;
  const int m0 = blockIdx.x * 128, n0 = blockIdx.y * 128;
  const int ar = tid >> 1, aq = (tid & 1) * 16;   // row 0..127, 16-short half (8 pairs)
  const int t_ = ar & 63;
  const int cc = blockIdx.x * 2 + (ar >> 6);
  const int brow = ((tid >> 6) << 4) | (tid & 15);
  const int bko = ((tid >> 4) & 3) * 8;
  const int frow = lane & 15, fk = (lane >> 4) * 8;
  const int hb = (wave & 1) * 2048;
  f32x4 acc[4][4];
#pragma unroll
  for (int i = 0; i < 4; i++)
#pragma unroll
    for (int j = 0; j < 4; j++) acc[i][j] = (f32x4){0.f, 0.f, 0.f, 0.f};

  // depth-3 reg pipelines, 2 named buffer sets (a/b), parity = tile&1
  uint4 x0a, x1a, x0b, x1b;
  float4 pra0, pra1, pia0, pia1, cra0, cra1, cia0, cia1;
  float4 prb0, prb1, pib0, pib1, crb0, crb1, cib0, cib1;
  const unsigned short* xbase = Xl + (size_t)(m0 + ar) * N1 + aq;
  const float* prb = powr + t_ * P;
  const float* pib = powi + t_ * P;
  const float* crb = car + cc * P;
  const float* cib = cai + cc * P;
#define LOAD_X(A0, A1, k0) { \
    A0 = *(const uint4*)(xbase + (k0)); A1 = *(const uint4*)(xbase + (k0) + 8); }
#define LOAD_PC(PR0, PR1, PI0, PI1, CR0, CR1, CI0, CI1, k0) { \
    const int p0_ = ((k0) >> 1) + (tid & 1) * 8; \
    PR0 = *(const float4*)(prb + p0_); PR1 = *(const float4*)(prb + p0_ + 4); \
    PI0 = *(const float4*)(pib + p0_); PI1 = *(const float4*)(pib + p0_ + 4); \
    CR0 = *(const float4*)(crb + p0_); CR1 = *(const float4*)(crb + p0_ + 4); \
    CI0 = *(const float4*)(cib + p0_); CI1 = *(const float4*)(cib + p0_ + 4); }
#define WRITE_A2(XA, XB, PR0, PR1, PI0, PI1, CR0, CR1, CI0, CI1, dst) { \
    unsigned xw[8] = {XA.x, XA.y, XA.z, XA.w, XB.x, XB.y, XB.z, XB.w}; \
    float pr_[8] = {PR0.x, PR0.y, PR0.z, PR0.w, PR1.x, PR1.y, PR1.z, PR1.w}; \
    float pi_[8] = {PI0.x, PI0.y, PI0.z, PI0.w, PI1.x, PI1.y, PI1.z, PI1.w}; \
    float cr_[8] = {CR0.x, CR0.y, CR0.z, CR0.w, CR1.x, CR1.y, CR1.z, CR1.w}; \
    float ci_[8] = {CI0.x, CI0.y, CI0.z, CI0.w, CI1.x, CI1.y, CI1.z, CI1.w}; \
    unsigned wo[8]; \
    _Pragma("unroll") for (int j_ = 0; j_ < 8; j_++) { \
      float xgr = bf_lo(xw[j_]) + (pr_[j_] * cr_[j_] - pi_[j_] * ci_[j_]); \
      float xgi = bf_hi(xw[j_]) + (pr_[j_] * ci_[j_] + pi_[j_] * cr_[j_]); \
      wo[j_] = f2bf(xgr) | (f2bf(xgi) << 16); } \
    uint4 w0, w1; \
    w0.x = wo[0]; w0.y = wo[1]; w0.z = wo[2]; w0.w = wo[3]; \
    w1.x = wo[4]; w1.y = wo[5]; w1.z = wo[6]; w1.w = wo[7]; \
    *(uint4*)((dst) + ar * LDA + aq) = w0; *(uint4*)((dst) + ar * LDA + aq + 8) = w1; }
#define ISSUE_B2(k0, buf) { \
    gload_lds16(Ccat + (size_t)(n0 + brow) * K + (k0) + bko, sB[buf] + tid * 8); \
    gload_lds16(Ccat + (size_t)(n0 + 64 + brow) * K + (k0) + bko, sB[buf] + 2048 + tid * 8); }

  // prologue. order: X0 PC0 X1 PC1 | B0 B1 B2 | (consume 0) X2 PC2
  LOAD_X(x0a, x1a, 0);
  LOAD_PC(pra0, pra1, pia0, pia1, cra0, cra1, cia0, cia1, 0);
  LOAD_X(x0b, x1b, 32);
  LOAD_PC(prb0, prb1, pib0, pib1, crb0, crb1, cib0, cib1, 32);
  VMEM_FENCE();
  ISSUE_B2(0, 0);
  ISSUE_B2(32, 1);
  ISSUE_B2(64, 2);
  VMEM_FENCE();
  WRITE_A2(x0a, x1a, pra0, pra1, pia0, pia1, cra0, cra1, cia0, cia1, sA[0]);
  LOAD_X(x0a, x1a, 64);
  LOAD_PC(pra0, pra1, pia0, pia1, cra0, cra1, cia0, cia1, 64);
  VMEM_FENCE();
  KBAR(14);   // wait B0: newer = B1(2)+B2(2)+X2(2)+PC2(8)
#pragma unroll
  for (int it = 0; it < NIT; it++) {
    if (it + 1 < NIT) {
      if (((it + 1) & 1) == 0) {
        WRITE_A2(x0a, x1a, pra0, pra1, pia0, pia1, cra0, cra1, cia0, cia1, sA[0]);
      } else {
        WRITE_A2(x0b, x1b, prb0, prb1, pib0, pib1, crb0, crb1, cib0, cib1, sA[1]);
      }
    }
    VMEM_FENCE();
    if (it + 3 < NIT) {
      if (((it + 3) & 1) == 0) {
        LOAD_X(x0a, x1a, (it + 3) * 32);
        LOAD_PC(pra0, pra1, pia0, pia1, cra0, cra1, cia0, cia1, (it + 3) * 32);
      } else {
        LOAD_X(x0b, x1b, (it + 3) * 32);
        LOAD_PC(prb0, prb1, pib0, pib1, crb0, crb1, cib0, cib1, (it + 3) * 32);
      }
    }
    VMEM_FENCE();
    if (it + 3 < NIT) ISSUE_B2((it + 3) * 32, (it + 3) & 3);
    VMEM_FENCE();
    short8 af[4], bfr[4];
#pragma unroll
    for (int i = 0; i < 4; i++) af[i] = *(const short8*)(sA[it & 1] + (wr + i * 16 + frow) * LDA + fk);
#pragma unroll
    for (int j = 0; j < 4; j++) bfr[j] = *(const short8*)(sB[it & 3] + hb + (j * 64 + lane) * 8);
#pragma unroll
    for (int i = 0; i < 4; i++)
#pragma unroll
      for (int j = 0; j < 4; j++)
        acc[i][j] = __builtin_amdgcn_mfma_f32_16x16x32_bf16(af[i], bfr[j], acc[i][j], 0, 0, 0);
    // wait B(it+1): steady newer = (X+PC+B)(it+2) 12 + (X+PC+B)(it+3) 12
    if (it + 1 < NIT) {
      if (it < NIT - 3) { KBAR(24); }
      else if (it == NIT - 3) { KBAR(12); }
      else { KBAR(0); }
    }
  }

  const int crow = wr + (lane >> 4) * 4, ccol = wc + (lane & 15);
  float dcol[4];
#pragma unroll
  for (int j = 0; j < 4; j++) dcol[j] = Dv[n0 + ccol + j * 16];
#pragma unroll
  for (int i = 0; i < 4; i++)
#pragma unroll
    for (int j = 0; j < 4; j++) {
      int col = n0 + ccol + j * 16;
#pragma unroll
      for (int g = 0; g < 4; g++) {
        int row = m0 + crow + i * 16 + g;
        out[(size_t)row * H + col] = acc[i][j][g] + dcol[j] * sig[(size_t)row * H + col];
      }
    }
#undef LOAD_X
#undef LOAD_PC
#undef WRITE_A2
#undef ISSUE_B2
}

// ---------------------------------------------------------------------------
// Launch
// ---------------------------------------------------------------------------
extern "C" void kernel_launch(void* const* d_in, const int* in_sizes, int n_in,
                              void* d_out, int out_size, void* d_ws, size_t ws_size,
                              hipStream_t stream) {
  const float* sig = (const float*)d_in[0];   // (L,H)
  const float* lam = (const float*)d_in[1];   // (P,2)
  const float* Bri = (const float*)d_in[2];   // (P,H,2)
  const float* Cri = (const float*)d_in[3];   // (H,P,2)
  const float* Dv  = (const float*)d_in[4];   // (H,)
  const float* lst = (const float*)d_in[5];   // (P,)
  float* out = (float*)d_out;

  unsigned short* Bcat = (unsigned short*)d_ws;             // N1*H bf16
  unsigned short* Ccat = Bcat + (size_t)N1 * H;             // H*N1 bf16
  unsigned short* Xl   = Ccat + (size_t)H * N1;             // L*N1 bf16 (x_local)
  float* powr = (float*)(Xl + (size_t)L * N1);              // T*P
  float* powi = powr + T * P;
  float* Sr   = powi + T * P;                               // P*NC (transposed)
  float* Si   = Sr + NC * P;
  float* car  = Si + NC * P;                                // NC*P
  float* cai  = car + NC * P;

  k_prep<<<(2 * N1 * H + T * P) / 256, 256, 0, stream>>>(lam, lst, Bri, Cri,
                                                         Bcat, Ccat, powr, powi);
  dim3 g1(L / 128, N1 / 128);
  k_gemm1s<<<g1, 256, 0, stream>>>(sig, Bcat, lam, lst, Xl, Sr, Si);
  k_carry2<<<NC / 2, 64, 0, stream>>>(lam, lst, Sr, Si, car, cai);
  dim3 g2(L / 128, H / 128);
  k_gemm2f<<<g2, 256, 0, stream>>>(Xl, Ccat, powr, powi, car, cai, sig, Dv, out);
}

// Round 3
// 152.403 us; speedup vs baseline: 1.0571x; 1.0571x over previous
//
#include <hip/hip_runtime.h>
#include <math.h>

constexpr int L = 32768;
constexpr int H = 256;
constexpr int P = 256;
constexpr int T = 64;        // scan chunk length
constexpr int NC = L / T;    // 512 chunks
constexpr int N1 = 2 * P;    // 512: X concat width, INTERLEAVED col = 2p+{0:re,1:im}
constexpr int LDA = 40;      // padded LDS A row stride (shorts) — used by gemm2 only
constexpr int LDEP = 130;    // epilogue LDS row stride (floats)

typedef __attribute__((ext_vector_type(8))) short short8;
typedef __attribute__((ext_vector_type(4))) float f32x4;

// ---------------- bf16 helpers (RNE) ----------------
__device__ __forceinline__ unsigned f2bf(float f) {
  unsigned u = __float_as_uint(f);
  return (u + 0x7FFFu + ((u >> 16) & 1u)) >> 16;
}
__device__ __forceinline__ float bf_lo(unsigned u) { return __uint_as_float(u << 16); }
__device__ __forceinline__ float bf_hi(unsigned u) { return __uint_as_float(u & 0xFFFF0000u); }

__device__ __forceinline__ void gload_lds16(const unsigned short* g, unsigned short* l) {
  __builtin_amdgcn_global_load_lds(
      (const __attribute__((address_space(1))) unsigned int*)(g),
      (__attribute__((address_space(3))) unsigned int*)(l), 16, 0, 0);
}

// Counted-vmcnt barrier: oldest needed gloads landed, deeper prefetches stay
// in flight. lgkmcnt(0) publishes ds_writes / completes ds_reads per wave.
#define KBAR(N) do { \
    asm volatile("s_waitcnt vmcnt(" #N ") lgkmcnt(0)" ::: "memory"); \
    __builtin_amdgcn_s_barrier(); \
    __builtin_amdgcn_sched_barrier(0); \
  } while (0)

// Pin VMEM issue order only (ALU/VALU/SALU/MFMA/DS may cross).
#define VMEM_FENCE() __builtin_amdgcn_sched_barrier(0x38F)

__device__ __forceinline__ void lambda_bar_of(const float* __restrict__ lam,
                                              const float* __restrict__ lstep,
                                              int p, float& lbr, float& lbi) {
  float lr = lam[2 * p], li = lam[2 * p + 1];
  float st = expf(lstep[p]);
  float ea = expf(lr * st);
  lbr = ea * cosf(li * st);
  lbi = ea * sinf(li * st);
}

// ---------------------------------------------------------------------------
// k_prep: Bcat (512 x 256 bf16), Ccat (256 x 512 bf16), pow (T x P fp32),
// PLUS sigt: sig converted to bf16 in FRAGMENT-MAJOR tile order:
//   sigt[panel][ks][c]*8shorts, panel=row/128, ks=k/32, chunk c in [0,512):
//   c -> row = 64*(c>>8) + 16*((c>>6)&3) + (c&15), kk = 8*((c>>4)&3).
// gemm1 then stages A with fully-coalesced global_load_lds (no VALU, no regs).
// ---------------------------------------------------------------------------
__global__ __launch_bounds__(256) void k_prep(const float* __restrict__ sig,
                                              const float* __restrict__ lam,
                                              const float* __restrict__ lstep,
                                              const float* __restrict__ Bri,
                                              const float* __restrict__ Cri,
                                              unsigned short* __restrict__ Bcat,
                                              unsigned short* __restrict__ Ccat,
                                              float* __restrict__ powr,
                                              float* __restrict__ powi,
                                              unsigned short* __restrict__ sigt) {
  int idx = blockIdx.x * 256 + threadIdx.x;  // < 1327104
  if (idx < N1 * H) {
    int n = idx >> 8, k = idx & 255;
    int p = n >> 1, comp = n & 1;
    float lr = lam[2 * p], li = lam[2 * p + 1];
    float st = expf(lstep[p]);
    float ea = expf(lr * st);
    float lbr = ea * cosf(li * st), lbi = ea * sinf(li * st);
    float inv = 1.0f / (lr * lr + li * li);
    float nr = lbr - 1.0f;
    float fr = (nr * lr + lbi * li) * inv;
    float fi = (lbi * lr - nr * li) * inv;
    float br = Bri[2 * (p * H + k)], bi = Bri[2 * (p * H + k) + 1];
    float v = (comp == 0) ? (fr * br - fi * bi) : (fr * bi + fi * br);
    Bcat[idx] = (unsigned short)f2bf(v);
  } else if (idx < 2 * N1 * H) {
    int j = idx - N1 * H;
    int h = j >> 9, k2 = j & 511;
    int p = k2 >> 1;
    float v = ((k2 & 1) == 0) ? Cri[2 * (h * P + p)] : -Cri[2 * (h * P + p) + 1];
    Ccat[j] = (unsigned short)f2bf(v);
  } else if (idx < 2 * N1 * H + T * P) {
    int r = idx - 2 * N1 * H;  // < T*P
    int t = r >> 8, p = r & 255;
    float lr = lam[2 * p], li = lam[2 * p + 1];
    float st = expf(lstep[p]);
    float e = (float)(t + 1);
    float er = expf(e * lr * st);
    powr[r] = er * cosf(e * li * st);
    powi[r] = er * sinf(e * li * st);
  } else {
    int C = idx - (2 * N1 * H + T * P);   // < 1048576 (one 16B chunk each)
    int panel = C >> 12;                   // 4096 chunks per 128-row panel
    int ks = (C >> 9) & 7;
    int c = C & 511;
    int row = ((c >> 8) << 6) + (((c >> 6) & 3) << 4) + (c & 15);
    int kk = ((c >> 4) & 3) << 3;
    const float* s = sig + (size_t)(panel * 128 + row) * 256 + ks * 32 + kk;
    float4 a = *(const float4*)(s);
    float4 b = *(const float4*)(s + 4);
    uint4 w;
    w.x = f2bf(a.x) | (f2bf(a.y) << 16);
    w.y = f2bf(a.z) | (f2bf(a.w) << 16);
    w.z = f2bf(b.x) | (f2bf(b.y) << 16);
    w.w = f2bf(b.z) | (f2bf(b.w) << 16);
    *(uint4*)(sigt + (size_t)C * 8) = w;
  }
}

// ---------------------------------------------------------------------------
// GEMM1 fused: 128x128 tile (2 chunks). BOTH operands via global_load_lds,
// fragment-major, conflict-free. A: 3-deep ring (HBM stream, 2-iter cover);
// B: 2-deep (L2-resident, 1-iter cover). LDS = 40 KB exactly -> 4 blocks/CU.
// Counted vmcnt: steady barrier waits vmcnt(2) only.
// Epilogue: per-chunk LDS dump + in-block scan -> Xl + S (S transposed [p][NC]).
// grid (L/128, N1/128) = (256, 4).
// ---------------------------------------------------------------------------
__global__ __launch_bounds__(256, 4) void k_gemm1s(const unsigned short* __restrict__ sigt,
                                                   const unsigned short* __restrict__ Bcat,
                                                   const float* __restrict__ lam,
                                                   const float* __restrict__ lstep,
                                                   unsigned short* __restrict__ Xl,
                                                   float* __restrict__ Sr,
                                                   float* __restrict__ Si) {
  constexpr int NIT = 8;   // K=256 / 32
  __shared__ __align__(16) char smem[40960];
  unsigned short* sA[3] = {(unsigned short*)smem, (unsigned short*)(smem + 8192),
                           (unsigned short*)(smem + 16384)};
  unsigned short* sB[2] = {(unsigned short*)(smem + 24576), (unsigned short*)(smem + 32768)};
  float* sEpi = (float*)smem;
  const int tid = threadIdx.x;
  const int lane = tid & 63;
  const int wave = tid >> 6;
  const int wc = (wave & 1) * 64;
  const int m0 = blockIdx.x * 128, n0 = blockIdx.y * 128;
  const int brow = ((tid >> 6) << 4) | (tid & 15);    // B staging source row
  const int bko = ((tid >> 4) & 3) * 8;               // B staging k-subgroup
  const int hb = (wave & 1) * 2048;                   // B half base (shorts)
  const int afb = (wave >> 1) * 256;                  // A frag chunk base
  const unsigned short* apan = sigt + (size_t)blockIdx.x * 32768;  // panel: 8 ks * 4096 shorts
  f32x4 acc[4][4];
#pragma unroll
  for (int i = 0; i < 4; i++)
#pragma unroll
    for (int j = 0; j < 4; j++) acc[i][j] = (f32x4){0.f, 0.f, 0.f, 0.f};

#define ISSUE_A1(ks, buf) { \
    gload_lds16(apan + (ks) * 4096 + tid * 8, sA[buf] + tid * 8); \
    gload_lds16(apan + (ks) * 4096 + 2048 + tid * 8, sA[buf] + 2048 + tid * 8); }
#define ISSUE_B1(ks, buf) { \
    gload_lds16(Bcat + (size_t)(n0 + brow) * 256 + (ks) * 32 + bko, sB[buf] + tid * 8); \
    gload_lds16(Bcat + (size_t)(n0 + 64 + brow) * 256 + (ks) * 32 + bko, sB[buf] + 2048 + tid * 8); }

  // prologue: issue A0(2) B0(2) A1(2); wait B0 -> vmcnt(2) leaves A1 in flight
  ISSUE_A1(0, 0);
  VMEM_FENCE();
  ISSUE_B1(0, 0);
  VMEM_FENCE();
  ISSUE_A1(1, 1);
  VMEM_FENCE();
  KBAR(2);
#pragma unroll
  for (int it = 0; it < NIT; it++) {
    if (it + 1 < NIT) ISSUE_B1(it + 1, (it + 1) & 1);
    VMEM_FENCE();
    if (it + 2 < NIT) ISSUE_A1(it + 2, (it + 2) % 3);
    VMEM_FENCE();
    const unsigned short* sAc = sA[it % 3];
    const unsigned short* sBc = sB[it & 1];
    short8 af[4], bfr[4];
#pragma unroll
    for (int i = 0; i < 4; i++) af[i] = *(const short8*)(sAc + (afb + i * 64 + lane) * 8);
#pragma unroll
    for (int j = 0; j < 4; j++) bfr[j] = *(const short8*)(sBc + hb + (j * 64 + lane) * 8);
#pragma unroll
    for (int i = 0; i < 4; i++)
#pragma unroll
      for (int j = 0; j < 4; j++)
        acc[i][j] = __builtin_amdgcn_mfma_f32_16x16x32_bf16(af[i], bfr[j], acc[i][j], 0, 0, 0);
    // wait B(it+1) (issued top of this iter); newer = A(it+2) 2 gloads
    if (it + 1 < NIT) {
      if (it + 2 < NIT) { KBAR(2); } else { KBAR(0); }
    }
  }
  __syncthreads();

  // ---- epilogue: per chunk-half: dump rows to LDS, scan, store ----
  const int crow = (lane >> 4) * 4, ccol = wc + (lane & 15);
#pragma unroll
  for (int half = 0; half < 2; half++) {
    if ((wave >> 1) == half) {
#pragma unroll
      for (int i = 0; i < 4; i++)
#pragma unroll
        for (int j = 0; j < 4; j++)
#pragma unroll
          for (int g = 0; g < 4; g++)
            sEpi[(crow + i * 16 + g) * LDEP + ccol + j * 16] = acc[i][j][g];
    }
    __syncthreads();
    if (tid < 64) {
      const int pl = tid;
      const int gp = (n0 >> 1) + pl;
      const int c = blockIdx.x * 2 + half;
      float lbr, lbi;
      lambda_bar_of(lam, lstep, gp, lbr, lbi);
      float xr = 0.f, xi = 0.f;
      const float* e = sEpi + 2 * pl;
      const size_t gbase = (size_t)(m0 + half * 64) * N1 + n0 + 2 * pl;
      for (int tb = 0; tb < T; tb += 8) {
        float2 v[8];
#pragma unroll
        for (int u = 0; u < 8; u++) v[u] = *(const float2*)(e + (tb + u) * LDEP);
        unsigned ov[8];
#pragma unroll
        for (int u = 0; u < 8; u++) {
          float nr = fmaf(lbr, xr, fmaf(-lbi, xi, v[u].x));
          float ni = fmaf(lbr, xi, fmaf(lbi, xr, v[u].y));
          xr = nr; xi = ni;
          ov[u] = f2bf(xr) | (f2bf(xi) << 16);
        }
#pragma unroll
        for (int u = 0; u < 8; u++)
          *(unsigned*)(Xl + gbase + (size_t)(tb + u) * N1) = ov[u];
      }
      Sr[(size_t)gp * NC + c] = xr;   // TRANSPOSED [p][NC]
      Si[(size_t)gp * NC + c] = xi;
    }
    __syncthreads();
  }
#undef ISSUE_A1
#undef ISSUE_B1
}

// ---------------------------------------------------------------------------
// Parallel carry scan: 256 blocks (one per p) x 64 threads (1 wave).
// S is [p][NC] -> vectorized contiguous loads.
// ---------------------------------------------------------------------------
__global__ __launch_bounds__(64) void k_carry2(const float* __restrict__ lam,
                                               const float* __restrict__ lstep,
                                               const float* __restrict__ Sr,
                                               const float* __restrict__ Si,
                                               float* __restrict__ car, float* __restrict__ cai) {
  const int p = blockIdx.x;
  const int t = threadIdx.x;  // 0..63
  float lr = lam[2 * p], li = lam[2 * p + 1];
  float st = expf(lstep[p]);
  float eT = expf((float)T * lr * st);
  float lTr = eT * cosf((float)T * li * st);
  float lTi = eT * sinf((float)T * li * st);
  float vr[8], vi[8];
  {
    const float* srp = Sr + (size_t)p * NC + t * 8;
    const float* sip = Si + (size_t)p * NC + t * 8;
    float4 a0 = *(const float4*)(srp), a1 = *(const float4*)(srp + 4);
    float4 b0 = *(const float4*)(sip), b1 = *(const float4*)(sip + 4);
    vr[0] = a0.x; vr[1] = a0.y; vr[2] = a0.z; vr[3] = a0.w;
    vr[4] = a1.x; vr[5] = a1.y; vr[6] = a1.z; vr[7] = a1.w;
    vi[0] = b0.x; vi[1] = b0.y; vi[2] = b0.z; vi[3] = b0.w;
    vi[4] = b1.x; vi[5] = b1.y; vi[6] = b1.z; vi[7] = b1.w;
  }
  float Br = 0.f, Bi = 0.f;
#pragma unroll
  for (int u = 0; u < 8; u++) {
    float nr = fmaf(lTr, Br, fmaf(-lTi, Bi, vr[u]));
    float ni = fmaf(lTr, Bi, fmaf(lTi, Br, vi[u]));
    Br = nr; Bi = ni;
  }
  float e8 = expf(8.0f * (float)T * lr * st);
  float Ar = e8 * cosf(8.0f * (float)T * li * st);
  float Ai = e8 * sinf(8.0f * (float)T * li * st);
#pragma unroll
  for (int d = 1; d < 64; d <<= 1) {
    float Aor = __shfl_up(Ar, d), Aoi = __shfl_up(Ai, d);
    float Bor = __shfl_up(Br, d), Boi = __shfl_up(Bi, d);
    if (t >= d) {
      float nBr = Ar * Bor - Ai * Boi + Br;
      float nBi = Ar * Boi + Ai * Bor + Bi;
      float nAr = Aor * Ar - Aoi * Ai;
      float nAi = Aor * Ai + Aoi * Ar;
      Br = nBr; Bi = nBi; Ar = nAr; Ai = nAi;
    }
  }
  float cr = __shfl_up(Br, 1), ci = __shfl_up(Bi, 1);
  if (t == 0) { cr = 0.f; ci = 0.f; }
#pragma unroll
  for (int u = 0; u < 8; u++) {
    car[(t * 8 + u) * P + p] = cr;
    cai[(t * 8 + u) * P + p] = ci;
    float nr = fmaf(lTr, cr, fmaf(-lTi, ci, vr[u]));
    float ni = fmaf(lTr, ci, fmaf(lTi, cr, vi[u]));
    cr = nr; ci = ni;
  }
}

// ---------------------------------------------------------------------------
// GEMM2 fused: 128x128 tile (2 chunks). B(Ccat): 4-deep LDS ring; X and
// pow/carry: depth-3 reg pipelines (2 bufs each). Counted vmcnt barriers.
// grid (L/128, H/128) = (256, 2).   [unchanged from round 2 — it improved]
// ---------------------------------------------------------------------------
__global__ __launch_bounds__(256, 3) void k_gemm2f(const unsigned short* __restrict__ Xl,
                                                   const unsigned short* __restrict__ Ccat,
                                                   const float* __restrict__ powr,
                                                   const float* __restrict__ powi,
                                                   const float* __restrict__ car,
                                                   const float* __restrict__ cai,
                                                   const float* __restrict__ sig,
                                                   const float* __restrict__ Dv,
                                                   float* __restrict__ out) {
  constexpr int K = 512, NIT = K / 32;
  __shared__ __align__(16) char smem[53248];
  unsigned short* sA[2] = {(unsigned short*)smem, (unsigned short*)smem + 5120};
  unsigned short* sB[4] = {(unsigned short*)(smem + 20480), (unsigned short*)(smem + 28672),
                           (unsigned short*)(smem + 36864), (unsigned short*)(smem + 45056)};
  const int tid = threadIdx.x;
  const int lane = tid & 63;
  const int wave = tid >> 6;
  const int wr = (wave >> 1) * 64, wc = (wave & 1) * 64;
  const int m0 = blockIdx.x * 128, n0 = blockIdx.y * 128;
  const int ar = tid >> 1, aq = (tid & 1) * 16;   // row 0..127, 16-short half (8 pairs)
  const int t_ = ar & 63;
  const int cc = blockIdx.x * 2 + (ar >> 6);
  const int brow = ((tid >> 6) << 4) | (tid & 15);
  const int bko = ((tid >> 4) & 3) * 8;
  const int frow = lane & 15, fk = (lane >> 4) * 8;
  const int hb = (wave & 1) * 2048;
  f32x4 acc[4][4];
#pragma unroll
  for (int i = 0; i < 4; i++)
#pragma unroll
    for (int j = 0; j < 4; j++) acc[i][j] = (f32x4){0.f, 0.f, 0.f, 0.f};

  // depth-3 reg pipelines, 2 named buffer sets (a/b), parity = tile&1
  uint4 x0a, x1a, x0b, x1b;
  float4 pra0, pra1, pia0, pia1, cra0, cra1, cia0, cia1;
  float4 prb0, prb1, pib0, pib1, crb0, crb1, cib0, cib1;
  const unsigned short* xbase = Xl + (size_t)(m0 + ar) * N1 + aq;
  const float* prb = powr + t_ * P;
  const float* pib = powi + t_ * P;
  const float* crb = car + cc * P;
  const float* cib = cai + cc * P;
#define LOAD_X(A0, A1, k0) { \
    A0 = *(const uint4*)(xbase + (k0)); A1 = *(const uint4*)(xbase + (k0) + 8); }
#define LOAD_PC(PR0, PR1, PI0, PI1, CR0, CR1, CI0, CI1, k0) { \
    const int p0_ = ((k0) >> 1) + (tid & 1) * 8; \
    PR0 = *(const float4*)(prb + p0_); PR1 = *(const float4*)(prb + p0_ + 4); \
    PI0 = *(const float4*)(pib + p0_); PI1 = *(const float4*)(pib + p0_ + 4); \
    CR0 = *(const float4*)(crb + p0_); CR1 = *(const float4*)(crb + p0_ + 4); \
    CI0 = *(const float4*)(cib + p0_); CI1 = *(const float4*)(cib + p0_ + 4); }
#define WRITE_A2(XA, XB, PR0, PR1, PI0, PI1, CR0, CR1, CI0, CI1, dst) { \
    unsigned xw[8] = {XA.x, XA.y, XA.z, XA.w, XB.x, XB.y, XB.z, XB.w}; \
    float pr_[8] = {PR0.x, PR0.y, PR0.z, PR0.w, PR1.x, PR1.y, PR1.z, PR1.w}; \
    float pi_[8] = {PI0.x, PI0.y, PI0.z, PI0.w, PI1.x, PI1.y, PI1.z, PI1.w}; \
    float cr_[8] = {CR0.x, CR0.y, CR0.z, CR0.w, CR1.x, CR1.y, CR1.z, CR1.w}; \
    float ci_[8] = {CI0.x, CI0.y, CI0.z, CI0.w, CI1.x, CI1.y, CI1.z, CI1.w}; \
    unsigned wo[8]; \
    _Pragma("unroll") for (int j_ = 0; j_ < 8; j_++) { \
      float xgr = bf_lo(xw[j_]) + (pr_[j_] * cr_[j_] - pi_[j_] * ci_[j_]); \
      float xgi = bf_hi(xw[j_]) + (pr_[j_] * ci_[j_] + pi_[j_] * cr_[j_]); \
      wo[j_] = f2bf(xgr) | (f2bf(xgi) << 16); } \
    uint4 w0, w1; \
    w0.x = wo[0]; w0.y = wo[1]; w0.z = wo[2]; w0.w = wo[3]; \
    w1.x = wo[4]; w1.y = wo[5]; w1.z = wo[6]; w1.w = wo[7]; \
    *(uint4*)((dst) + ar * LDA + aq) = w0; *(uint4*)((dst) + ar * LDA + aq + 8) = w1; }
#define ISSUE_B2(k0, buf) { \
    gload_lds16(Ccat + (size_t)(n0 + brow) * K + (k0) + bko, sB[buf] + tid * 8); \
    gload_lds16(Ccat + (size_t)(n0 + 64 + brow) * K + (k0) + bko, sB[buf] + 2048 + tid * 8); }

  // prologue. order: X0 PC0 X1 PC1 | B0 B1 B2 | (consume 0) X2 PC2
  LOAD_X(x0a, x1a, 0);
  LOAD_PC(pra0, pra1, pia0, pia1, cra0, cra1, cia0, cia1, 0);
  LOAD_X(x0b, x1b, 32);
  LOAD_PC(prb0, prb1, pib0, pib1, crb0, crb1, cib0, cib1, 32);
  VMEM_FENCE();
  ISSUE_B2(0, 0);
  ISSUE_B2(32, 1);
  ISSUE_B2(64, 2);
  VMEM_FENCE();
  WRITE_A2(x0a, x1a, pra0, pra1, pia0, pia1, cra0, cra1, cia0, cia1, sA[0]);
  LOAD_X(x0a, x1a, 64);
  LOAD_PC(pra0, pra1, pia0, pia1, cra0, cra1, cia0, cia1, 64);
  VMEM_FENCE();
  KBAR(14);   // wait B0: newer = B1(2)+B2(2)+X2(2)+PC2(8)
#pragma unroll
  for (int it = 0; it < NIT; it++) {
    if (it + 1 < NIT) {
      if (((it + 1) & 1) == 0) {
        WRITE_A2(x0a, x1a, pra0, pra1, pia0, pia1, cra0, cra1, cia0, cia1, sA[0]);
      } else {
        WRITE_A2(x0b, x1b, prb0, prb1, pib0, pib1, crb0, crb1, cib0, cib1, sA[1]);
      }
    }
    VMEM_FENCE();
    if (it + 3 < NIT) {
      if (((it + 3) & 1) == 0) {
        LOAD_X(x0a, x1a, (it + 3) * 32);
        LOAD_PC(pra0, pra1, pia0, pia1, cra0, cra1, cia0, cia1, (it + 3) * 32);
      } else {
        LOAD_X(x0b, x1b, (it + 3) * 32);
        LOAD_PC(prb0, prb1, pib0, pib1, crb0, crb1, cib0, cib1, (it + 3) * 32);
      }
    }
    VMEM_FENCE();
    if (it + 3 < NIT) ISSUE_B2((it + 3) * 32, (it + 3) & 3);
    VMEM_FENCE();
    short8 af[4], bfr[4];
#pragma unroll
    for (int i = 0; i < 4; i++) af[i] = *(const short8*)(sA[it & 1] + (wr + i * 16 + frow) * LDA + fk);
#pragma unroll
    for (int j = 0; j < 4; j++) bfr[j] = *(const short8*)(sB[it & 3] + hb + (j * 64 + lane) * 8);
#pragma unroll
    for (int i = 0; i < 4; i++)
#pragma unroll
      for (int j = 0; j < 4; j++)
        acc[i][j] = __builtin_amdgcn_mfma_f32_16x16x32_bf16(af[i], bfr[j], acc[i][j], 0, 0, 0);
    // wait B(it+1): steady newer = (X+PC+B)(it+2) 12 + (X+PC+B)(it+3) 12
    if (it + 1 < NIT) {
      if (it < NIT - 3) { KBAR(24); }
      else if (it == NIT - 3) { KBAR(12); }
      else { KBAR(0); }
    }
  }

  const int crow = wr + (lane >> 4) * 4, ccol = wc + (lane & 15);
  float dcol[4];
#pragma unroll
  for (int j = 0; j < 4; j++) dcol[j] = Dv[n0 + ccol + j * 16];
#pragma unroll
  for (int i = 0; i < 4; i++)
#pragma unroll
    for (int j = 0; j < 4; j++) {
      int col = n0 + ccol + j * 16;
#pragma unroll
      for (int g = 0; g < 4; g++) {
        int row = m0 + crow + i * 16 + g;
        out[(size_t)row * H + col] = acc[i][j][g] + dcol[j] * sig[(size_t)row * H + col];
      }
    }
#undef LOAD_X
#undef LOAD_PC
#undef WRITE_A2
#undef ISSUE_B2
}

// ---------------------------------------------------------------------------
// Launch
// ---------------------------------------------------------------------------
extern "C" void kernel_launch(void* const* d_in, const int* in_sizes, int n_in,
                              void* d_out, int out_size, void* d_ws, size_t ws_size,
                              hipStream_t stream) {
  const float* sig = (const float*)d_in[0];   // (L,H)
  const float* lam = (const float*)d_in[1];   // (P,2)
  const float* Bri = (const float*)d_in[2];   // (P,H,2)
  const float* Cri = (const float*)d_in[3];   // (H,P,2)
  const float* Dv  = (const float*)d_in[4];   // (H,)
  const float* lst = (const float*)d_in[5];   // (P,)
  float* out = (float*)d_out;

  unsigned short* Bcat = (unsigned short*)d_ws;             // N1*H bf16
  unsigned short* Ccat = Bcat + (size_t)N1 * H;             // H*N1 bf16
  unsigned short* Xl   = Ccat + (size_t)H * N1;             // L*N1 bf16 (x_local)
  float* powr = (float*)(Xl + (size_t)L * N1);              // T*P
  float* powi = powr + T * P;
  float* Sr   = powi + T * P;                               // P*NC (transposed)
  float* Si   = Sr + NC * P;
  float* car  = Si + NC * P;                                // NC*P
  float* cai  = car + NC * P;
  unsigned short* sigt = (unsigned short*)(cai + NC * P);   // L*H bf16, tile order

  k_prep<<<(2 * N1 * H + T * P + L * H / 8) / 256, 256, 0, stream>>>(
      sig, lam, lst, Bri, Cri, Bcat, Ccat, powr, powi, sigt);
  dim3 g1(L / 128, N1 / 128);
  k_gemm1s<<<g1, 256, 0, stream>>>(sigt, Bcat, lam, lst, Xl, Sr, Si);
  k_carry2<<<NC / 2, 64, 0, stream>>>(lam, lst, Sr, Si, car, cai);
  dim3 g2(L / 128, H / 128);
  k_gemm2f<<<g2, 256, 0, stream>>>(Xl, Ccat, powr, powi, car, cai, sig, Dv, out);
}